// Round 15
// baseline (2698.592 us; speedup 1.0000x reference)
//
#include <hip/hip_runtime.h>
#include <math.h>

#define NPTS 3072
#define BLK  256
#define NW   4
#define NKB  48         // fallback batches: 48*64 = 3072
#define NCLS 10

#pragma clang fp contract(off)

typedef float v2f __attribute__((ext_vector_type(2)));

__device__ __forceinline__ unsigned umin32(unsigned a, unsigned b) { return a < b ? a : b; }

// 64-lane min-reduce via DPP butterfly; result valid in lane 63 (R6-R14-proven).
__device__ __forceinline__ unsigned dppmin_u32(unsigned x) {
    unsigned t;
    t = (unsigned)__builtin_amdgcn_update_dpp(-1, (int)x, 0x111, 0xF, 0xF, false); x = x < t ? x : t; // row_shr:1
    t = (unsigned)__builtin_amdgcn_update_dpp(-1, (int)x, 0x112, 0xF, 0xF, false); x = x < t ? x : t; // row_shr:2
    t = (unsigned)__builtin_amdgcn_update_dpp(-1, (int)x, 0x114, 0xF, 0xF, false); x = x < t ? x : t; // row_shr:4
    t = (unsigned)__builtin_amdgcn_update_dpp(-1, (int)x, 0x118, 0xF, 0xF, false); x = x < t ? x : t; // row_shr:8
    t = (unsigned)__builtin_amdgcn_update_dpp(-1, (int)x, 0x142, 0xF, 0xF, false); x = x < t ? x : t; // row_bcast:15
    t = (unsigned)__builtin_amdgcn_update_dpp(-1, (int)x, 0x143, 0xF, 0xF, false); x = x < t ? x : t; // row_bcast:31
    return x;
}

__global__ __launch_bounds__(BLK)
void frustum_cluster(const float* __restrict__ pts,
                     const int* __restrict__ lblg,
                     const float* __restrict__ anch,
                     int* __restrict__ out,
                     int* __restrict__ ws)
{
    const int tid  = threadIdx.x;
    const int lane = tid & 63;
    const int wid  = tid >> 6;

    // ---------------- global workspace ----------------
    int*    dlg    = ws + 16;                          // 3072 ints: per-point label
    float4* gstats = (float4*)(ws + 8192);             // per-cluster stats

    // ---------------- LDS ----------------
    __shared__ float4 gpts[NPTS];                      // class-grouped points; epilogue: ordered clusters
    __shared__ unsigned short vor16[NPTS];             // visit order; epilogue: bucket counts
    __shared__ unsigned short startv[NPTS];            // run starts; epilogue: bucket ids, then remap16
    __shared__ float amdxy[NCLS], amdz[NCLS];
    __shared__ unsigned vthr[NCLS], wthr[NCLS];        // sqrt-free compare thresholds
    __shared__ int cntL[NCLS], curL[NCLS], baseL[NCLS];
    __shared__ int cntC[NCLS], curC[NCLS], baseC[NCLS];
    __shared__ int p0s, nclusS;

    if (tid < NCLS) {
        float l = anch[tid*3+0], w = anch[tid*3+1], h = anch[tid*3+2];
        amdxy[tid] = fmaxf(l, w);
        amdz[tid]  = h;
        float r2 = sqrtf((l*l + w*w) + h*h) * 0.5f;    // norm(anchor)/2, ref op order
        // V: largest float bits v with sqrtf(v) <= r2  =>  (sqrtf(s) > r2) == (bits(s) > V)
        unsigned lo = 0u, hi = 0x7F7FFFFFu;
        while (hi - lo > 1u) {
            unsigned mid = lo + ((hi - lo) >> 1);
            if (sqrtf(__uint_as_float(mid)) <= r2) lo = mid; else hi = mid;
        }
        vthr[tid] = lo;
        // W: largest float bits w with sqrtf(w) < r2  =>  (sqrtf(s) < r2) == (bits(s) <= W)
        lo = 0u; hi = 0x7F7FFFFFu;
        while (hi - lo > 1u) {
            unsigned mid = lo + ((hi - lo) >> 1);
            if (sqrtf(__uint_as_float(mid)) < r2) lo = mid; else hi = mid;
        }
        wthr[tid] = lo;
        cntL[tid] = 0; curL[tid] = 0; cntC[tid] = 0; curC[tid] = 0;
    }
    __syncthreads();
    for (int j = tid; j < NPTS; j += BLK) atomicAdd(&cntL[lblg[j]], 1);
    __syncthreads();
    if (tid == 0) { int acc = 0; for (int c = 0; c < NCLS; ++c) { baseL[c] = acc; acc += cntL[c]; } }
    __syncthreads();
    // scatter into class-grouped layout; w = prebaked meta (id<<16 | cls<<12 | pos)
    for (int j = tid; j < NPTS; j += BLK) {
        int c = lblg[j];
        int pos = baseL[c] + atomicAdd(&curL[c], 1);
        float4 e;
        e.x = pts[3*j]; e.y = pts[3*j+1]; e.z = pts[3*j+2];
        e.w = __uint_as_float(((unsigned)j << 16) | ((unsigned)c << 12) | (unsigned)pos);
        gpts[pos] = e;
        if (j == 0) p0s = pos;
    }
    if (tid == 0) startv[0] = 0;
    __syncthreads();   // scatter + p0s visible; waves 1-3 fall through to the join barrier

    // ================= single-wave scan: wave 0, ZERO barriers =================
    if (wid == 0) {
        // lane-parked class constants (readlane fetch at walk reload only)
        float axyL = 0.f, azL = 0.f; int vLn = 0, baseLn = 0, cntLn = 0;
        if (lane < NCLS) {
            axyL = amdxy[lane]; azL = amdz[lane];
            vLn = (int)vthr[lane]; baseLn = baseL[lane]; cntLn = cntL[lane];
        }
        const int p0 = p0s;
        int pos = p0;
        int cls = lblg[0];
        unsigned walked = 1u << cls;
        bool doReload = true;
        int live = 0, base_c = 0, cnt_c = 0, npairs = 4;
        // slot pairs (class points, loop-invariant within a walk); poison x=3e19 -> ss=+inf
        v2f sx2[4], sy2[4], sz2[4];
        unsigned mmr[8];
        float pcx = pts[0], pcy = pts[1], pcz = pts[2];
        float sx = pcx, sy = pcy, sz = pcz, scnt = 1.0f;
        float icx = pcx, icy = pcy, icz = pcz;
        int lab = 0;
        float amdxy_c = 0.f, amdz_c = 0.f; unsigned Vc = 0;
        if (lane == 0) vor16[0] = (unsigned short)p0;

        for (int t = 0; t < NPTS-1; ++t) {
            if (doReload) {                            // 10x total: walk start
                base_c = __builtin_amdgcn_readlane(baseLn, cls);
                cnt_c  = __builtin_amdgcn_readlane(cntLn, cls);
                #pragma unroll
                for (int j = 0; j < 4; ++j) {
                    #pragma unroll
                    for (int h = 0; h < 2; ++h) {
                        int s = 2*j + h;
                        int off = lane + (s << 6);
                        int p = base_c + off;
                        bool in = off < cnt_c;
                        float4 e = gpts[in ? p : 0];
                        bool v = in && (p != pos);     // fresh class: only current point visited
                        float px = v ? e.x : 3e19f;    // poisoned slot: ss -> +inf
                        float py = v ? e.y : 0.f;
                        float pz = v ? e.z : 0.f;
                        if (h == 0) { sx2[j].x = px; sy2[j].x = py; sz2[j].x = pz; }
                        else        { sx2[j].y = px; sy2[j].y = py; sz2[j].y = pz; }
                        mmr[s] = in ? __float_as_uint(e.w) : 0xFFFFFFFFu;  // sentinel (R13 fix)
                    }
                }
                amdxy_c = __int_as_float(__builtin_amdgcn_readlane(__float_as_int(axyL), cls));
                amdz_c  = __int_as_float(__builtin_amdgcn_readlane(__float_as_int(azL), cls));
                Vc = (unsigned)__builtin_amdgcn_readlane(vLn, cls);
                live = cnt_c - 1;
                npairs = (cnt_c <= 6*64) ? 3 : 4;      // 3-pair fast path covers <=384 (classes ~307)
                doReload = false;
            }
            unsigned kbest, mbest;
            if (live > 0) {
                // in-walk sweep: packed-f32 register VALU (pk_mul/pk_add: IEEE-exact per half)
                #define INWALK(NP) do {                                                   \
                    v2f ss2[4];                                                           \
                    _Pragma("unroll")                                                     \
                    for (int j = 0; j < (NP); ++j) {                                      \
                        v2f dx = pcx - sx2[j], dy = pcy - sy2[j], dz = pcz - sz2[j];      \
                        ss2[j] = (dx*dx + dy*dy) + dz*dz;  /* ref order, contract off */  \
                    }                                                                     \
                    float m = fminf(ss2[0].x, ss2[0].y);                                  \
                    _Pragma("unroll")                                                     \
                    for (int j = 1; j < (NP); ++j) m = fminf(m, fminf(ss2[j].x, ss2[j].y));\
                    kbest = __float_as_uint(m);        /* nonneg: bit order == value */   \
                    mbest = 0xFFFFFFFFu;                                                  \
                    _Pragma("unroll")                                                     \
                    for (int j = 0; j < (NP); ++j) {                                      \
                        mbest = umin32(mbest, (ss2[j].x == m) ? mmr[2*j]   : 0xFFFFFFFFu);\
                        mbest = umin32(mbest, (ss2[j].y == m) ? mmr[2*j+1] : 0xFFFFFFFFu);\
                    }                                                                     \
                } while (0)
                if (npairs == 3) { INWALK(3); } else { INWALK(4); }
                #undef INWALK
            } else {
                // fallback (9x total): nearest point of any un-walked class (pen uniform -> drops)
                kbest = 0xFFFFFFFFu; mbest = 0xFFFFFFFFu;
                for (int k = 0; k < NKB; ++k) {
                    int p = lane + (k << 6);
                    float4 e = gpts[p];
                    unsigned meta = __float_as_uint(e.w);
                    float dx = pcx - e.x, dy = pcy - e.y, dz = pcz - e.z;
                    float s = (dx*dx + dy*dy) + dz*dz;
                    unsigned key = __float_as_uint(s);
                    bool ok = !((walked >> ((meta >> 12) & 15u)) & 1u);
                    if (ok && (key < kbest || (key == kbest && meta < mbest))) {
                        kbest = key; mbest = meta;
                    }
                }
            }
            // in-wave argmin: DPP on key; exact ties -> min meta (orig idx dominates)
            unsigned wk = (unsigned)__builtin_amdgcn_readlane((int)dppmin_u32(kbest), 63);
            bool cand = (kbest == wk);
            unsigned long long msk = __ballot(cand);
            if (msk & (msk - 1)) {
                unsigned wm2 = (unsigned)__builtin_amdgcn_readlane(
                    (int)dppmin_u32(cand ? mbest : 0xFFFFFFFFu), 63);
                msk = __ballot(cand && mbest == wm2);
            }
            int wl = __ffsll((unsigned long long)msk) - 1;
            unsigned wm = (unsigned)__builtin_amdgcn_readlane((int)mbest, wl);
            pos = (int)(wm & 0xFFFu);
            int clsE = (int)((wm >> 12) & 15u);
            // winner coords: one wave-uniform LDS broadcast read (replaces cndmask recovery)
            float4 we = gpts[pos];
            float pix = we.x, piy = we.y, piz = we.z;
            bool nc;
            if (live > 0) {                            // in-walk: clsE == cls structurally
                float dx = pcx - pix, dy = pcy - piy, dz = pcz - piz;
                nc = (fabsf(dx) > amdxy_c) || (fabsf(dy) > amdxy_c) || (fabsf(dz) > amdz_c);
                nc = nc || (wk > Vc);                  // winner key == bits(s): d > r2 sqrt-free
                float ex = icx - pix, ey = icy - piy, ez = icz - piz;
                float seC = (ex*ex + ey*ey) + ez*ez;
                nc = nc || (__float_as_uint(seC) > Vc);
                live -= 1;
                // poison winner's slot: slot index is wave-uniform -> 1 predicated store
                int offw = pos - base_c;
                int iw = offw >> 6;
                bool me = (lane == (offw & 63));
                switch (iw) {
                    case 0: if (me) sx2[0].x = 3e19f; break;
                    case 1: if (me) sx2[0].y = 3e19f; break;
                    case 2: if (me) sx2[1].x = 3e19f; break;
                    case 3: if (me) sx2[1].y = 3e19f; break;
                    case 4: if (me) sx2[2].x = 3e19f; break;
                    case 5: if (me) sx2[2].y = 3e19f; break;
                    case 6: if (me) sx2[3].x = 3e19f; break;
                    default: if (me) sx2[3].y = 3e19f; break;
                }
            } else {                                   // fallback: clsE != cls -> always new cluster
                nc = true;
                walked |= 1u << clsE;
                cls = clsE;
                doReload = true;
            }
            if (nc) {
                lab += 1;
                if (lane == 0) startv[lab] = (unsigned short)(t + 1);
                sx = pix; sy = piy; sz = piz; scnt = 1.0f;
                icx = pix; icy = piy; icz = piz;       // sx/1 == sx exactly: no divide
            } else {
                sx = sx + pix; sy = sy + piy; sz = sz + piz; scnt = scnt + 1.0f;
                icx = sx / scnt; icy = sy / scnt; icz = sz / scnt;
            }
            if (lane == 0) vor16[t+1] = (unsigned short)pos;
            pcx = pix; pcy = piy; pcz = piz;
        }
        if (lane == 0) nclusS = lab;
    }
    __syncthreads();   // join: waves 1-3 parked here during the scan
    const int nclus = nclusS;

    // ---------------- epilogue (R11-R14-proven, unchanged; gpts untouched by scan) ----------------
    // (a) runs in visit order -> per-cluster stats (bitwise == scan's incremental sums) + dl to global
    for (int c2 = tid; c2 <= nclus; c2 += BLK) {
        int s0 = startv[c2];
        int s1e = (c2 < nclus) ? (int)startv[c2+1] : NPTS;
        float ax = 0.f, ay = 0.f, az = 0.f;
        int clsF = 0;
        for (int s = s0; s < s1e; ++s) {
            float4 e = gpts[vor16[s]];
            unsigned pk = __float_as_uint(e.w);
            if (s == s0) clsF = (int)((pk >> 12) & 15u);
            ax = ax + e.x; ay = ay + e.y; az = az + e.z;
            dlg[pk >> 16] = c2;
        }
        if (c2 < nclus) {
            float fc = (float)(s1e - s0);
            float4 g;
            g.x = ax / fc; g.y = ay / fc; g.z = az / fc;
            g.w = __uint_as_float(((unsigned)(s1e - s0) << 4) | (unsigned)clsF);
            gstats[c2] = g;
        }
    }
    __syncthreads();

    // (a2) bucket counts per class over clusters
    for (int c2 = tid; c2 < nclus; c2 += BLK)
        atomicAdd(&cntC[__float_as_uint(gstats[c2].w) & 15u], 1);
    __syncthreads();
    if (tid == 0) { int acc = 0; for (int c = 0; c < NCLS; ++c) { baseC[c] = acc; acc += cntC[c]; } }
    __syncthreads();

    // (b) scatter clusters into class buckets (vor16 = count, startv = cluster id)
    for (int c2 = tid; c2 < nclus; c2 += BLK) {
        unsigned gw = __float_as_uint(gstats[c2].w);
        int cl = (int)(gw & 15u);
        int slot = baseC[cl] + atomicAdd(&curC[cl], 1);
        vor16[slot]  = (unsigned short)(gw >> 4);
        startv[slot] = (unsigned short)c2;
    }
    __syncthreads();

    // (c) class-local stable rank (counts desc, id asc) -> ordered bucket entries in gpts
    for (int slot = tid; slot < nclus; slot += BLK) {
        int cl = 0;
        #pragma unroll
        for (int q = 1; q < NCLS; ++q) cl += (int)(slot >= baseC[q]);
        int b0 = baseC[cl], b1 = b0 + cntC[cl];
        int cnt = (int)vor16[slot], id = (int)startv[slot];
        int r = 0;
        for (int s2 = b0; s2 < b1; ++s2) {
            int cnt2 = (int)vor16[s2], id2 = (int)startv[s2];
            r += (int)((cnt2 > cnt) || (cnt2 == cnt && id2 < id));
        }
        float4 g = gstats[id];
        float4 oe;
        oe.x = g.x; oe.y = g.y; oe.z = g.z;
        oe.w = __uint_as_float(((unsigned)id << 1) | 1u);   // id | kept-bit (class implicit)
        gpts[b0 + r] = oe;
    }
    __syncthreads();

    // (d) remap16 identity (startv reused)
    unsigned short* remap16 = startv;
    for (int c2 = tid; c2 < NPTS; c2 += BLK) remap16[c2] = (unsigned short)c2;
    __syncthreads();

    // (e) per-class merge: classes independent; wave w handles classes w, w+4, w+8 — zero barriers
    for (int cl = wid; cl < NCLS; cl += NW) {
        int b0 = baseC[cl], b1 = b0 + cntC[cl];
        unsigned Wc = wthr[cl];
        for (int i = b0; i < b1; ++i) {
            float4 ei = gpts[i];
            unsigned wi = __float_as_uint(ei.w);
            if (wi & 1u) {                             // kept -> active absorber
                int orgI = (int)(wi >> 1);
                for (int j = i + 1 + lane; j < b1; j += 64) {
                    float4 ej = gpts[j];
                    unsigned wj = __float_as_uint(ej.w);
                    if (wj & 1u) {
                        float ddx = ej.x - ei.x, ddy = ej.y - ei.y, ddz = ej.z - ei.z;
                        float sdd = (ddx*ddx + ddy*ddy) + ddz*ddz;
                        if (__float_as_uint(sdd) <= Wc) {   // == (sqrtf(sdd) < r2_cl)
                            gpts[j].w = __uint_as_float(wj & ~1u);
                            remap16[wj >> 1] = (unsigned short)orgI;
                        }
                    }
                }
            }
        }
    }
    __syncthreads();

    // (f) final relabel
    for (int p = tid; p < NPTS; p += BLK) out[p] = (int)remap16[dlg[p]];
}

extern "C" void kernel_launch(void* const* d_in, const int* in_sizes, int n_in,
                              void* d_out, int out_size, void* d_ws, size_t ws_size,
                              hipStream_t stream) {
    const float* pts  = (const float*)d_in[0];   // [3072,3] f32
    const int*   lbl  = (const int*)d_in[1];     // [3072] i32
    const float* anch = (const float*)d_in[2];   // [10,3] f32
    frustum_cluster<<<dim3(1), dim3(BLK), 0, stream>>>(pts, lbl, anch,
                                                       (int*)d_out, (int*)d_ws);
}